// Round 7
// baseline (422.193 us; speedup 1.0000x reference)
//
#include <hip/hip_runtime.h>
#include <hip/hip_bf16.h>

// a_mean_op: out = where(deg>0, segment_mean(relu(h @ W.T + b)[src], dst), hr)
// R7: (1) fill rewritten as pure-atomic (atomicSub cursor + atomicExch store):
//     R6 showed plain scattered 4B stores cost full 64B lines (WRITE 107MB for
//     a 6.4MB buffer) while atomics are serviced memory-side at 8B. (2) GEMM
//     fused into the hist dispatch (W is L2-resident, converted during staging;
//     Wb buffer dropped). (3) cursor = inclusive scan replaces rowptr+deg pair
//     in fill.

#define FEAT 128

using bf16 = __hip_bfloat16;
typedef __attribute__((ext_vector_type(8))) short short8_;   // 8 x bf16
typedef __attribute__((ext_vector_type(4))) short bhalf4;    // 4 x bf16
typedef __attribute__((ext_vector_type(4))) float floatx4;

__device__ __forceinline__ bhalf4 cvt4(float4 f) {
    bhalf4 s;
    s[0] = __bfloat16_as_short(__float2bfloat16(f.x));
    s[1] = __bfloat16_as_short(__float2bfloat16(f.y));
    s[2] = __bfloat16_as_short(__float2bfloat16(f.z));
    s[3] = __bfloat16_as_short(__float2bfloat16(f.w));
    return s;
}
__device__ __forceinline__ float4 b2f4(bhalf4 s) {
    float4 f;
    f.x = __bfloat162float(__short_as_bfloat16(s[0]));
    f.y = __bfloat162float(__short_as_bfloat16(s[1]));
    f.z = __bfloat162float(__short_as_bfloat16(s[2]));
    f.w = __bfloat162float(__short_as_bfloat16(s[3]));
    return f;
}

// ---------------------------------------------------------------------------
// K0: fused [GEMM hr = bf16(relu(h @ W^T + b))] + [deg histogram].
// GEMM blocks first (long pole). W fp32 is 64KB -> L2-resident across blocks;
// converted to bf16 during LDS staging. hist blocks: 4 edges/thread atomics.
// ---------------------------------------------------------------------------
#define BM 64
__launch_bounds__(256)
__global__ void gemm_hist_kernel(const float* __restrict__ h, const float* __restrict__ W,
                                 const float* __restrict__ b, bf16* __restrict__ hr, int M,
                                 const int* __restrict__ dst, int* __restrict__ deg, int E,
                                 int gb) {
    __shared__ bf16 sA[BM][136];
    __shared__ bf16 sW[FEAT][136];

    if (blockIdx.x >= gb) {
        // ---- histogram ----
        int base = ((blockIdx.x - gb) * 256 + threadIdx.x) * 4;
        #pragma unroll
        for (int i = 0; i < 4; ++i) {
            int e = base + i;
            if (e < E) atomicAdd(&deg[dst[e]], 1);
        }
        return;
    }

    const int tid  = threadIdx.x;
    const int row0 = blockIdx.x * BM;

    // stage W (fp32 -> bf16): 4096 float4, 16 per thread (L2-hot after warmup)
    #pragma unroll
    for (int i = 0; i < 16; ++i) {
        int v = i * 256 + tid;
        int r = v >> 5;                 // 32 float4 per row
        int c = (v & 31) * 4;
        *(bhalf4*)(&sW[r][c]) = cvt4(*(const float4*)(W + (size_t)r * FEAT + c));
    }
    // stage A (fp32 -> bf16): 2048 float4, 8 per thread
    #pragma unroll
    for (int i = 0; i < 8; ++i) {
        int v = i * 256 + tid;
        int r = v >> 5;
        int c = (v & 31) * 4;
        int row = row0 + r;
        float4 f = make_float4(0.f, 0.f, 0.f, 0.f);
        if (row < M) f = *(const float4*)(h + (size_t)row * FEAT + c);
        *(bhalf4*)(&sA[r][c]) = cvt4(f);
    }
    __syncthreads();

    const int wave = tid >> 6;
    const int lane = tid & 63;
    const int m    = lane & 15;
    const int ko   = (lane >> 4) * 8;

    floatx4 acc[8];
    #pragma unroll
    for (int t = 0; t < 8; ++t) acc[t] = floatx4{0.f, 0.f, 0.f, 0.f};

    #pragma unroll
    for (int k0 = 0; k0 < FEAT; k0 += 32) {
        short8_ afrag = *(const short8_*)(&sA[wave * 16 + m][k0 + ko]);
        #pragma unroll
        for (int nt = 0; nt < 8; ++nt) {
            short8_ bfrag = *(const short8_*)(&sW[nt * 16 + m][k0 + ko]);
            acc[nt] = __builtin_amdgcn_mfma_f32_16x16x32_bf16(afrag, bfrag, acc[nt], 0, 0, 0);
        }
    }

    const int rbase = row0 + wave * 16 + (lane >> 4) * 4;
    #pragma unroll
    for (int nt = 0; nt < 8; ++nt) {
        int col = nt * 16 + m;
        float bias = b[col];
        #pragma unroll
        for (int r = 0; r < 4; ++r) {
            int row = rbase + r;
            if (row < M) {
                float v = fmaxf(acc[nt][r] + bias, 0.0f);
                hr[(size_t)row * FEAT + col] = __float2bfloat16(v);
            }
        }
    }
}

// ---------------------------------------------------------------------------
// K1: per-block (1024-entry) partial sums of deg.
// ---------------------------------------------------------------------------
__launch_bounds__(256)
__global__ void scan_partial_kernel(const int* __restrict__ deg, int* __restrict__ bsum, int N) {
    __shared__ int sdata[256];
    int base = blockIdx.x * 1024;
    int t = threadIdx.x;
    int s = 0;
    #pragma unroll
    for (int i = 0; i < 4; ++i) {
        int idx = base + t * 4 + i;
        if (idx < N) s += deg[idx];
    }
    sdata[t] = s;
    __syncthreads();
    for (int off = 128; off > 0; off >>= 1) {
        if (t < off) sdata[t] += sdata[t + off];
        __syncthreads();
    }
    if (t == 0) bsum[blockIdx.x] = sdata[0];
}

// ---------------------------------------------------------------------------
// K2: exclusive scan of block sums (NB <= 256), one block.
// ---------------------------------------------------------------------------
__launch_bounds__(256)
__global__ void scan_bsums_kernel(int* __restrict__ bsum, int nb) {
    __shared__ int sdata[256];
    int t = threadIdx.x;
    int v = (t < nb) ? bsum[t] : 0;
    sdata[t] = v;
    __syncthreads();
    for (int off = 1; off < 256; off <<= 1) {
        int y = (t >= off) ? sdata[t - off] : 0;
        __syncthreads();
        sdata[t] += y;
        __syncthreads();
    }
    if (t < nb) bsum[t] = sdata[t] - v;
}

// ---------------------------------------------------------------------------
// K3: rowptr (exclusive, for gather) + cursor (inclusive, for fill).
// ---------------------------------------------------------------------------
__launch_bounds__(256)
__global__ void scan_final_kernel(const int* __restrict__ deg, const int* __restrict__ bsum,
                                  int* __restrict__ rowptr, int* __restrict__ cursor,
                                  int N, int E) {
    __shared__ int sdata[256];
    int base = blockIdx.x * 1024;
    int t = threadIdx.x;
    int v[4];
    int s = 0;
    #pragma unroll
    for (int i = 0; i < 4; ++i) {
        int idx = base + t * 4 + i;
        v[i] = (idx < N) ? deg[idx] : 0;
        s += v[i];
    }
    sdata[t] = s;
    __syncthreads();
    for (int off = 1; off < 256; off <<= 1) {
        int y = (t >= off) ? sdata[t - off] : 0;
        __syncthreads();
        sdata[t] += y;
        __syncthreads();
    }
    int excl = sdata[t] - s + bsum[blockIdx.x];
    #pragma unroll
    for (int i = 0; i < 4; ++i) {
        int idx = base + t * 4 + i;
        if (idx < N) {
            rowptr[idx] = excl;
            cursor[idx] = excl + v[i];
        }
        excl += v[i];
    }
    if (blockIdx.x == 0 && t == 0) rowptr[N] = E;
}

// ---------------------------------------------------------------------------
// K4: fill, pure-atomic. atomicSub on cursor assigns the slot; atomicExch
// writes the slot memory-side (8B) instead of dirtying a 64B line.
// ---------------------------------------------------------------------------
__launch_bounds__(256)
__global__ void fill_kernel(const int* __restrict__ src, const int* __restrict__ dst,
                            int* __restrict__ cursor, int* __restrict__ eidx, int E) {
    int e = blockIdx.x * 256 + threadIdx.x;
    if (e >= E) return;
    int d = dst[e];
    int old = atomicSub(&cursor[d], 1);      // old in (rowptr[d], rowptr[d]+deg]
    atomicExch(&eidx[old - 1], src[e]);
}

// ---------------------------------------------------------------------------
// K5: gather (R6 version). One wave/node, half-wave per edge, 8B loads,
// 8 edges in flight, shfl_xor(32) combine.
// ---------------------------------------------------------------------------
__launch_bounds__(256)
__global__ void gather_kernel(const bf16* __restrict__ hr,
                              const int* __restrict__ rowptr,
                              const int* __restrict__ eidx,
                              float* __restrict__ out, int N) {
    int node = blockIdx.x * 4 + (threadIdx.x >> 6);
    if (node >= N) return;
    int lane = threadIdx.x & 63;
    int half = lane >> 5;
    int l32  = lane & 31;

    int beg = rowptr[node];
    int end = rowptr[node + 1];

    const bhalf4* hp4 = (const bhalf4*)hr;   // 32 per row
    float4 a0 = make_float4(0.f,0.f,0.f,0.f), a1 = make_float4(0.f,0.f,0.f,0.f);
    float4 a2 = make_float4(0.f,0.f,0.f,0.f), a3 = make_float4(0.f,0.f,0.f,0.f);

    int e = beg;
    for (; e + 7 < end; e += 8) {
        int s0 = eidx[e + 0 + half];
        int s1 = eidx[e + 2 + half];
        int s2 = eidx[e + 4 + half];
        int s3 = eidx[e + 6 + half];
        float4 f0 = b2f4(hp4[(size_t)s0 * 32 + l32]);
        float4 f1 = b2f4(hp4[(size_t)s1 * 32 + l32]);
        float4 f2 = b2f4(hp4[(size_t)s2 * 32 + l32]);
        float4 f3 = b2f4(hp4[(size_t)s3 * 32 + l32]);
        a0.x += f0.x; a0.y += f0.y; a0.z += f0.z; a0.w += f0.w;
        a1.x += f1.x; a1.y += f1.y; a1.z += f1.z; a1.w += f1.w;
        a2.x += f2.x; a2.y += f2.y; a2.z += f2.z; a2.w += f2.w;
        a3.x += f3.x; a3.y += f3.y; a3.z += f3.z; a3.w += f3.w;
    }
    for (; e < end; e += 2) {
        int ei = e + half;
        if (ei < end) {
            int s0 = eidx[ei];
            float4 f0 = b2f4(hp4[(size_t)s0 * 32 + l32]);
            a0.x += f0.x; a0.y += f0.y; a0.z += f0.z; a0.w += f0.w;
        }
    }

    a0.x += a1.x + a2.x + a3.x;
    a0.y += a1.y + a2.y + a3.y;
    a0.z += a1.z + a2.z + a3.z;
    a0.w += a1.w + a2.w + a3.w;
    a0.x += __shfl_xor(a0.x, 32, 64);
    a0.y += __shfl_xor(a0.y, 32, 64);
    a0.z += __shfl_xor(a0.z, 32, 64);
    a0.w += __shfl_xor(a0.w, 32, 64);

    int d = end - beg;
    float4 r;
    if (d > 0) {
        float inv = 1.0f / (float)d;
        r.x = a0.x * inv; r.y = a0.y * inv; r.z = a0.z * inv; r.w = a0.w * inv;
    } else {
        r = b2f4(hp4[(size_t)node * 32 + l32]);
    }
    if (half == 0)
        *(float4*)(out + (size_t)node * FEAT + l32 * 4) = r;
}

// ---------------------------------------------------------------------------
extern "C" void kernel_launch(void* const* d_in, const int* in_sizes, int n_in,
                              void* d_out, int out_size, void* d_ws, size_t ws_size,
                              hipStream_t stream) {
    const float* h   = (const float*)d_in[0];
    const int*   src = (const int*)d_in[2];
    const int*   dst = (const int*)d_in[3];
    const float* W   = (const float*)d_in[4];
    const float* b   = (const float*)d_in[5];
    float* out = (float*)d_out;

    const int N = in_sizes[0] / FEAT;
    const int E = in_sizes[2];
    const int NB = (N + 1023) / 1024;

    // ws: hr bf16[N*128] | rowptr int[N+1] | cursor int[N] | deg int[N]
    //   | eidx int[E] | bsum int[NB]
    char* ws = (char*)d_ws;
    size_t off = 0;
    bf16* hr     = (bf16*)(ws + off); off += (size_t)N * FEAT * 2;
    int*  rowptr = (int*)(ws + off);  off += (size_t)(N + 1) * 4;
    int*  cursor = (int*)(ws + off);  off += (size_t)N * 4;
    int*  deg    = (int*)(ws + off);  off += (size_t)N * 4;
    int*  eidx   = (int*)(ws + off);  off += (size_t)E * 4;
    int*  bsum   = (int*)(ws + off);  off += (size_t)NB * 4;

    (void)hipMemsetAsync(deg, 0, (size_t)N * 4, stream);

    const int gb  = (N + BM - 1) / BM;
    const int cbe = (E + 1023) / 1024;
    gemm_hist_kernel<<<dim3(gb + cbe), dim3(256), 0, stream>>>(
        h, W, b, hr, N, dst, deg, E, gb);

    scan_partial_kernel<<<dim3(NB), dim3(256), 0, stream>>>(deg, bsum, N);
    scan_bsums_kernel<<<dim3(1), dim3(256), 0, stream>>>(bsum, NB);
    scan_final_kernel<<<dim3(NB), dim3(256), 0, stream>>>(deg, bsum, rowptr, cursor, N, E);
    fill_kernel<<<dim3((E + 255) / 256), dim3(256), 0, stream>>>(src, dst, cursor, eidx, E);
    gather_kernel<<<dim3((N + 3) / 4), dim3(256), 0, stream>>>(hr, rowptr, eidx, out, N);
}